// Round 5
// baseline (309.027 us; speedup 1.0000x reference)
//
#include <hip/hip_runtime.h>
#include <hip/hip_bf16.h>
#include <math.h>

#define IN_F  256
#define OUT_F 64

typedef __attribute__((ext_vector_type(8))) short bf16x8;
typedef __attribute__((ext_vector_type(4))) float f32x4;

__device__ inline unsigned short f2b(float x) {
    union { __hip_bfloat16 h; unsigned short u; } cv;
    cv.h = __float2bfloat16(x);
    return cv.u;
}
__device__ inline float b2f_lo(unsigned int u) { return __uint_as_float(u << 16); }
__device__ inline float b2f_hi(unsigned int u) { return __uint_as_float(u & 0xffff0000u); }

// ---------------------------------------------------------------------------
// 1. CSR row_ptr from sorted rows
// ---------------------------------------------------------------------------
__global__ void rowptr_kernel(const int* __restrict__ rows,
                              int* __restrict__ row_ptr,
                              int n_rows, int n_edges) {
    int r = blockIdx.x * blockDim.x + threadIdx.x;
    if (r > n_rows) return;
    if (r == n_rows) { row_ptr[n_rows] = n_edges; return; }
    int lo = 0, hi = n_edges;
    while (lo < hi) {
        int mid = (lo + hi) >> 1;
        if (rows[mid] < r) lo = mid + 1; else hi = mid;
    }
    row_ptr[r] = lo;
}

// ---------------------------------------------------------------------------
// 1b. Weight convert: fp32 [k=256][n=64] -> bf16 transposed wt[n=64][k=256].
//     One thread per element; 32 KB output stays L2-resident for the GEMM.
// ---------------------------------------------------------------------------
__global__ void wcvt_kernel(const float* __restrict__ w,
                            unsigned short* __restrict__ wt) {
    int t = blockIdx.x * 256 + threadIdx.x;     // 0..16383
    int k = t >> 6, n = t & 63;
    wt[n * IN_F + k] = f2b(w[t]);
}

// ---------------------------------------------------------------------------
// 2. sup_bf = bf16(tanh(feat @ w)) — MFMA bf16, no LDS, no syncthreads.
//    Wave = 16 nodes; block = 4 waves = 64 nodes -> grid ~1563 (6 blocks/CU).
//    A-frag: fp32 feat rows + packed cvt; B-frag: b128 from wt (L1/L2-hot).
//    C/D: col=lane&15, row=quad*4+reg (measured m89/m91).
// ---------------------------------------------------------------------------
__global__ __launch_bounds__(256, 4) void gemm_tanh_kernel(
    const float* __restrict__ feat,            // [N, 256]
    const unsigned short* __restrict__ wt,     // [64][256] bf16 bits
    const int* __restrict__ active,            // [1]
    unsigned short* __restrict__ sup_bf,       // [N, 64] bf16 bits
    int N)
{
    const int lane = threadIdx.x & 63;
    const int m    = lane & 15;
    const int quad = lane >> 4;
    const int node0 = (blockIdx.x * 4 + (threadIdx.x >> 6)) * 16;
    if (node0 >= N) return;

    int nd = node0 + m;
    if (nd > N - 1) nd = N - 1;                // clamp; OOB rows never stored
    const float* arow = feat + (size_t)nd * IN_F;

    f32x4 acc[4];
    #pragma unroll
    for (int nt = 0; nt < 4; ++nt) acc[nt] = (f32x4)0.0f;

    #pragma unroll
    for (int kt = 0; kt < 8; ++kt) {
        const int ko = kt * 32 + quad * 8;
        f32x4 lo = *(const f32x4*)(arow + ko);
        f32x4 hi = *(const f32x4*)(arow + ko + 4);
        bf16x8 a;
        a[0] = (short)f2b(lo[0]); a[1] = (short)f2b(lo[1]);
        a[2] = (short)f2b(lo[2]); a[3] = (short)f2b(lo[3]);
        a[4] = (short)f2b(hi[0]); a[5] = (short)f2b(hi[1]);
        a[6] = (short)f2b(hi[2]); a[7] = (short)f2b(hi[3]);
        #pragma unroll
        for (int nt = 0; nt < 4; ++nt) {
            bf16x8 b = *(const bf16x8*)(wt + (size_t)(nt * 16 + m) * IN_F + ko);
            acc[nt] = __builtin_amdgcn_mfma_f32_16x16x32_bf16(a, b, acc[nt], 0, 0, 0);
        }
    }

    int act = __builtin_amdgcn_readfirstlane(active[0]);
    #pragma unroll
    for (int r = 0; r < 4; ++r) {
        int node = node0 + quad * 4 + r;
        if (node >= N) continue;
        #pragma unroll
        for (int nt = 0; nt < 4; ++nt) {
            float v = acc[nt][r];
            if (act) v = tanhf(v);
            sup_bf[(size_t)node * OUT_F + nt * 16 + m] = f2b(v);
        }
    }
}

// ---------------------------------------------------------------------------
// 3. SpMM: out[r,:] = sum_e vals[e] * x[cols[e],:]
//    Wave per row; half-wave per edge (2 edges/gather), lane holds 2 cols.
//    Main loop: 16 edges = 8 independent gathers in flight. Edge metadata
//    wave-uniform -> s_load. Cross-half combine via shfl_xor(32).
// ---------------------------------------------------------------------------
__device__ inline int lower_bound(const int* __restrict__ a, int n, int key) {
    int lo = 0, hi = n;
    while (lo < hi) {
        int mid = (lo + hi) >> 1;
        if (a[mid] < key) lo = mid + 1; else hi = mid;
    }
    return lo;
}

template <bool XBF>
__global__ __launch_bounds__(256) void spmm_kernel(
    const int* __restrict__ row_ptr,          // [N+1] or null
    const int* __restrict__ rows,             // [E] sorted (fallback)
    const int* __restrict__ cols,             // [E]
    const float* __restrict__ vals,           // [E]
    const void* __restrict__ x,               // [N,64] bf16 or fp32
    float* __restrict__ out,                  // [N,64] fp32
    unsigned short* __restrict__ out_bf,      // [N,64] bf16 or null
    int N, int E)
{
    const int wv   = __builtin_amdgcn_readfirstlane((int)(threadIdx.x >> 6));
    const int row  = blockIdx.x * 4 + wv;
    const int lane = threadIdx.x & 63;
    const int h    = lane >> 5;       // half
    const int l    = lane & 31;       // lane in half -> cols {2l, 2l+1}
    if (row >= N) return;

    int s, e;
    if (row_ptr) { s = row_ptr[row]; e = row_ptr[row + 1]; }
    else         { s = lower_bound(rows, E, row); e = lower_bound(rows, E, row + 1); }

    const unsigned short* xb = (const unsigned short*)x;
    const float*          xf = (const float*)x;

    float ax = 0.0f, ay = 0.0f;
    int i = s;
    for (; i + 16 <= e; i += 16) {
        #pragma unroll
        for (int p = 0; p < 8; ++p) {
            int   c0 = cols[i + 2 * p],     c1 = cols[i + 2 * p + 1];
            float v0 = vals[i + 2 * p],     v1 = vals[i + 2 * p + 1];
            int   c  = h ? c1 : c0;
            float v  = h ? v1 : v0;
            if (XBF) {
                unsigned int r2 = *(const unsigned int*)(xb + (size_t)c * OUT_F + 2 * l);
                ax = fmaf(v, b2f_lo(r2), ax);
                ay = fmaf(v, b2f_hi(r2), ay);
            } else {
                float2 r2 = *(const float2*)(xf + (size_t)c * OUT_F + 2 * l);
                ax = fmaf(v, r2.x, ax);
                ay = fmaf(v, r2.y, ay);
            }
        }
    }
    for (; i + 2 <= e; i += 2) {
        int   c0 = cols[i],  c1 = cols[i + 1];
        float v0 = vals[i],  v1 = vals[i + 1];
        int   c  = h ? c1 : c0;
        float v  = h ? v1 : v0;
        if (XBF) {
            unsigned int r2 = *(const unsigned int*)(xb + (size_t)c * OUT_F + 2 * l);
            ax = fmaf(v, b2f_lo(r2), ax);
            ay = fmaf(v, b2f_hi(r2), ay);
        } else {
            float2 r2 = *(const float2*)(xf + (size_t)c * OUT_F + 2 * l);
            ax = fmaf(v, r2.x, ax);
            ay = fmaf(v, r2.y, ay);
        }
    }
    if (i < e) {   // odd edge: half1 contributes 0
        int   c = cols[i];
        float v = h ? 0.0f : vals[i];
        if (XBF) {
            unsigned int r2 = *(const unsigned int*)(xb + (size_t)c * OUT_F + 2 * l);
            ax = fmaf(v, b2f_lo(r2), ax);
            ay = fmaf(v, b2f_hi(r2), ay);
        } else {
            float2 r2 = *(const float2*)(xf + (size_t)c * OUT_F + 2 * l);
            ax = fmaf(v, r2.x, ax);
            ay = fmaf(v, r2.y, ay);
        }
    }

    ax += __shfl_xor(ax, 32, 64);
    ay += __shfl_xor(ay, 32, 64);

    if (h == 0) {
        size_t base = (size_t)row * OUT_F + 2 * l;
        *(float2*)(out + base) = make_float2(ax, ay);
        if (out_bf) {
            unsigned int pk = (unsigned int)f2b(ax) | ((unsigned int)f2b(ay) << 16);
            *(unsigned int*)(out_bf + base) = pk;
        }
    }
}

// ---------------------------------------------------------------------------
extern "C" void kernel_launch(void* const* d_in, const int* in_sizes, int n_in,
                              void* d_out, int out_size, void* d_ws, size_t ws_size,
                              hipStream_t stream) {
    const float* feat   = (const float*)d_in[0];   // [N,256] fp32
    const float* w      = (const float*)d_in[1];   // [256,64] fp32
    const int*   rows   = (const int*)d_in[2];     // [E] sorted
    const int*   cols   = (const int*)d_in[3];     // [E]
    const float* vals   = (const float*)d_in[4];   // [E] fp32
    const int*   active = (const int*)d_in[5];     // [1]

    const int N = in_sizes[0] / IN_F;   // 100000
    const int E = in_sizes[2];          // 1600000

    float* out = (float*)d_out;                    // [output | az] fp32
    float* az  = out + (size_t)N * OUT_F;

    // ws layout: row_ptr | wt | sup_bf | mid_bf  (tiered fallbacks)
    size_t rp_bytes = (((size_t)(N + 1) * sizeof(int)) + 255) & ~(size_t)255;
    size_t wt_bytes = (((size_t)IN_F * OUT_F * sizeof(unsigned short)) + 255) & ~(size_t)255;
    size_t bf_bytes = (((size_t)N * OUT_F * sizeof(unsigned short)) + 255) & ~(size_t)255;
    char* ws = (char*)d_ws;

    int* row_ptr = nullptr;
    unsigned short *wt, *sup_bf, *mid_bf = nullptr;
    size_t used = 0;
    if (ws_size >= rp_bytes) { row_ptr = (int*)ws; used += rp_bytes; }
    if (ws_size >= used + wt_bytes + bf_bytes) {
        wt = (unsigned short*)(ws + used); used += wt_bytes;
        sup_bf = (unsigned short*)(ws + used); used += bf_bytes;
        if (ws_size >= used + bf_bytes) mid_bf = (unsigned short*)(ws + used);
    } else {
        // az half of d_out as scratch: wt at az, sup_bf after it.
        // Both are dead before spmm2 writes az (stream-serialized).
        wt = (unsigned short*)az;
        sup_bf = (unsigned short*)((char*)az + wt_bytes);
    }

    if (row_ptr) {
        int threads = N + 1;
        rowptr_kernel<<<(threads + 255) / 256, 256, 0, stream>>>(rows, row_ptr, N, E);
    }
    wcvt_kernel<<<(IN_F * OUT_F) / 256, 256, 0, stream>>>(w, wt);

    {   // sup_bf = bf16(tanh(feat @ w))
        int blocks = (N + 63) / 64;
        gemm_tanh_kernel<<<blocks, 256, 0, stream>>>(feat, wt, active, sup_bf, N);
    }

    int spmm_blocks = (N + 3) / 4;
    // output = A @ support (gather bf16; emit bf16 copy if room)
    spmm_kernel<true><<<spmm_blocks, 256, 0, stream>>>(
        row_ptr, rows, cols, vals, sup_bf, out, mid_bf, N, E);
    // az = A @ output
    if (mid_bf) {
        spmm_kernel<true><<<spmm_blocks, 256, 0, stream>>>(
            row_ptr, rows, cols, vals, mid_bf, az, nullptr, N, E);
    } else {
        spmm_kernel<false><<<spmm_blocks, 256, 0, stream>>>(
            row_ptr, rows, cols, vals, out, az, nullptr, N, E);
    }
}